// Round 13
// baseline (425.109 us; speedup 1.0000x reference)
//
#include <hip/hip_runtime.h>

typedef _Float16 f16x4 __attribute__((ext_vector_type(4)));
typedef float    f32x4 __attribute__((ext_vector_type(4)));

#define NROWS  300000
#define NTILES (NROWS/16)      // 18750
#define WPB    8
#define TPB    512
#define NBLK   ((NTILES + WPB - 1) / WPB)  // 2344

// weight-lo plane pre-scaled by 2^11 (stays out of f16-denormal range)
#define LSCALE     2048.0f
#define INV_LSCALE 4.8828125e-4f   // 2^-11 exact

#define RS64   136
#define LO64   72
#define RS128  264
#define LO128  136

// ---- d_ws weight-image offsets (halves); identical to R12.
#define IMG_P1 0        // FC1@0, FC2@8704
#define IMG_P2 17408    // FC3 cols 0..127
#define IMG_P3 34816    // FC3 cols 128..255
#define IMG_P4 52224    // TP1@0, TP2@8704, TP4@17408
#define IMG_P5 78336    // LIN0
#define IMG_P6 95232    // TP3@0, LIN1@8704

// ---- LDS: double buffer only (no bounce buffer needed in transpose-chain)
#define BUFSZ  26112
#define OFF_A  0
#define OFF_B  BUFSZ
#define LDS_HALVES (2*BUFSZ)   // 52224 halves = 104448 B
static_assert(LDS_HALVES * 2 <= 160*1024, "LDS overflow");

struct apair { f16x4 h, l; };   // weight A-frag (h; l pre-scaled x2048)
struct bpair { f16x4 h, l; };   // activation B-frag
struct h2    { _Float16 h, l; };
struct acc2  { f32x4 m, l; };

__device__ __forceinline__ f32x4 MFMA16(f16x4 a, f16x4 b, f32x4 c) {
  return __builtin_amdgcn_mfma_f32_16x16x16f16(a, b, c, 0, 0, 0);
}

// transposed split-GEMM step: A=weight pair, B=act pair
//   c.m += Wh*ah + Wh*al   (main + act-lo)
//   c.l += Wl*ah           (weight-lo, x2048 plane)
__device__ __forceinline__ void gemmT(const apair& a, const bpair& b, acc2& c) {
  c.m = MFMA16(a.h, b.h, c.m);
  c.m = MFMA16(a.h, b.l, c.m);
  c.l = MFMA16(a.l, b.h, c.l);
}
__device__ __forceinline__ f32x4 fin(const acc2& c) { return c.m + c.l * INV_LSCALE; }

// weight A-frag: lane holds W^T[nt*16+(lane&15)][ks*16 + 4*kgrp + j], j=0..3
// = image[(nt*16+n)*RS + k] -> two ds_read_b64 (hi plane, lo plane)
__device__ __forceinline__ apair afrag(const _Float16* w, int RS, int LO,
                                       int nt, int ks, int lane) {
  const _Float16* base = w + (nt*16 + (lane & 15))*RS + ks*16 + ((lane >> 4) << 2);
  apair r;
  r.h = *(const f16x4*)base;
  r.l = *(const f16x4*)(base + LO);
  return r;
}

__device__ __forceinline__ h2 split1(float v) {
  h2 r;
  r.h = (_Float16)v;
  r.l = (_Float16)(v - (float)r.h);
  return r;
}

__device__ __forceinline__ bpair splitB(f32x4 v) {
  bpair r;
#pragma unroll
  for (int i = 0; i < 4; ++i) {
    h2 t = split1(v[i]);
    r.h[i] = t.h; r.l[i] = t.l;
  }
  return r;
}

// async copy of a 1KB-granular weight image into LDS (wave-striped)
__device__ __forceinline__ void copyimg(_Float16* ldsdst, const _Float16* gsrc,
                                        int nch, int wave, int lane) {
  for (int c = wave; c < nch; c += WPB)
    __builtin_amdgcn_global_load_lds(
        (const __attribute__((address_space(1))) void*)(gsrc + c*512 + lane*8),
        (__attribute__((address_space(3))) void*)(ldsdst + c*512), 16, 0, 0);
}

// ---------- prep kernel: identical to R12 ----------
__global__ __launch_bounds__(256) void prep_w(
    const float* __restrict__ Wtp1, const float* __restrict__ Wtp2,
    const float* __restrict__ Wtp3, const float* __restrict__ Wtp4,
    const float* __restrict__ Wfc1, const float* __restrict__ Wfc2,
    const float* __restrict__ Wfc3, const float* __restrict__ Wlin0,
    const float* __restrict__ Wlin1, _Float16* __restrict__ ws)
{
  int e = blockIdx.x*256 + threadIdx.x;   // 0..57343
  const float INV8 = 0.125f, INVS3 = 0.57735026918962576f, INVSMD = 0.08838834764831845f;
  const float* W; int u, n; _Float16* dst; int RS, LOo; float sc;
  if (e < 4096)       { int l = e;        u=l>>6; n=l&63;  W=Wfc1 +u*64+n;  dst=ws+IMG_P1;       RS=RS64;  LOo=LO64;  sc=INV8; }
  else if (e < 8192)  { int l = e-4096;   u=l>>6; n=l&63;  W=Wfc2 +u*64+n;  dst=ws+IMG_P1+8704;  RS=RS64;  LOo=LO64;  sc=INV8; }
  else if (e < 24576) { int l = e-8192;   u=l>>8; n=l&255; W=Wfc3 +u*256+n; RS=RS64; LOo=LO64; sc=INV8;
                        if (n < 128) dst = ws+IMG_P2; else { dst = ws+IMG_P3; n -= 128; } }
  else if (e < 28672) { int l = e-24576;  u=l>>6; n=l&63;  W=Wtp1 +u*64+n;  dst=ws+IMG_P4;       RS=RS64;  LOo=LO64;  sc=INV8; }
  else if (e < 32768) { int l = e-28672;  u=l>>6; n=l&63;  W=Wtp2 +u*64+n;  dst=ws+IMG_P4+8704;  RS=RS64;  LOo=LO64;  sc=INV8; }
  else if (e < 36864) { int l = e-32768;  u=l>>6; n=l&63;  W=Wtp4 +u*64+n;  dst=ws+IMG_P4+17408; RS=RS64;  LOo=LO64;  sc=INV8*INVS3; }
  else if (e < 45056) { int l = e-36864;  u=l>>6; n=l&63;  W=Wlin0+u*64+n;  dst=ws+IMG_P5;       RS=RS128; LOo=LO128; sc=INVSMD; }
  else if (e < 49152) { int l = e-45056;  u=l>>6; n=l&63;  W=Wtp3 +u*64+n;  dst=ws+IMG_P6;       RS=RS64;  LOo=LO64;  sc=INV8; }
  else                { int l = e-49152;  u=l>>6; n=l&63;  W=Wlin1+u*64+n;  dst=ws+IMG_P6+8704;  RS=RS128; LOo=LO128; sc=INVSMD; }
  float v = (*W) * sc;
  _Float16 h = (_Float16)v;
  float res = (v - (float)h) * LSCALE;
  dst[n*RS + u]       = h;
  dst[n*RS + LOo + u] = (_Float16)res;
}

// bound 2: bound-4 proven to corrupt numerics via register pressure (R9 vs R10).
__global__ __launch_bounds__(TPB, 2) void tp_fused(
    const float* __restrict__ x,    const float* __restrict__ y,
    const float* __restrict__ sc,
    const _Float16* __restrict__ wsrc, float* __restrict__ out)
{
  __shared__ _Float16 lds[LDS_HALVES];
  const int tid  = threadIdx.x;
  const int lane = tid & 63;
  const int wave = tid >> 6;
  const int tile = blockIdx.x * WPB + wave;
  const bool active = (tile < NTILES);
  const int r0   = (active ? tile : 0) * 16;
  const int arow = lane & 15;
  const int kgrp = lane >> 4;
  const int rowg = r0 + arow;    // every lane owns THIS data row throughout
  _Float16* bufA = lds + OFF_A;
  _Float16* bufB = lds + OFF_B;

  // ---------- P1 copy (startup) ----------
  copyimg(bufA, wsrc + IMG_P1, 34, wave, lane);

  // ---- per-lane y of own row (single 16B load; no shfl needed in T-form) ----
  f32x4 yr = *(const f32x4*)(y + rowg*4);
  const float y0A = yr[0], y1A0 = yr[1], y1A1 = yr[2], y1A2 = yr[3];

  // ---- sc act in B-frag T-form: lane's row, features ks*16+kgrp*4+(0..3) ----
  const float* scp = sc + rowg*64;
  bpair SC[4];
#pragma unroll
  for (int ks = 0; ks < 4; ++ks)
    SC[ks] = splitB(*(const f32x4*)(scp + ks*16 + kgrp*4));

  __syncthreads();                                   // P1 ready
  copyimg(bufB, wsrc + IMG_P2, 34, wave, lane);      // P2 under MLP

  // ================= MLP: z^T = FC1^T @ sc^T (zero-shuffle chain) ============
  bpair H[4];
#pragma unroll
  for (int nt = 0; nt < 4; ++nt) {
    acc2 c{};
#pragma unroll
    for (int ks = 0; ks < 4; ++ks)
      gemmT(afrag(bufA, RS64, LO64, nt, ks, lane), SC[ks], c);
    f32x4 v = fin(c);
#pragma unroll
    for (int i = 0; i < 4; ++i) v[i] = v[i] / (1.f + __expf(-v[i]));
    H[nt] = splitB(v);
  }
  bpair H2[4];
#pragma unroll
  for (int nt = 0; nt < 4; ++nt) {
    acc2 c{};
#pragma unroll
    for (int ks = 0; ks < 4; ++ks)
      gemmT(afrag(bufA + 8704, RS64, LO64, nt, ks, lane), H[ks], c);
    f32x4 v = fin(c);
#pragma unroll
    for (int i = 0; i < 4; ++i) v[i] = v[i] / (1.f + __expf(-v[i]));
    H2[nt] = splitB(v);
  }

  __syncthreads();                                   // A free, P2 arrived
  copyimg(bufA, wsrc + IMG_P3, 34, wave, lane);      // P3 under FC3h1

  f32x4 wv[16];   // w^T: wv[t] = features 16t+4kgrp+(0..3) of lane's row
#pragma unroll
  for (int nt = 0; nt < 8; ++nt) {
    acc2 c{};
#pragma unroll
    for (int ks = 0; ks < 4; ++ks)
      gemmT(afrag(bufB, RS64, LO64, nt, ks, lane), H2[ks], c);
    wv[nt] = fin(c);
  }

  __syncthreads();                                   // B free, P3 arrived
  copyimg(bufB, wsrc + IMG_P4, 51, wave, lane);      // P4 under FC3h2

#pragma unroll
  for (int nt = 0; nt < 8; ++nt) {
    acc2 c{};
#pragma unroll
    for (int ks = 0; ks < 4; ++ks)
      gemmT(afrag(bufA, RS64, LO64, nt, ks, lane), H2[ks], c);
    wv[8 + nt] = fin(c);
  }

  __syncthreads();                                   // A free, P4 arrived
  copyimg(bufA, wsrc + IMG_P5, 33, wave, lane);      // P5 under TP phase

  // ================= x-dependent GEMMs (TP1@B, TP2@B+8704, TP4@B+17408) ======
  const float* xr = x + rowg*256;
  bpair X[4], Xa[4];
#pragma unroll
  for (int ks = 0; ks < 4; ++ks) {
    f32x4 v = *(const f32x4*)(xr + ks*16 + kgrp*4);
    X[ks]  = splitB(v);
    Xa[ks] = splitB(v * y0A);
  }

  f32x4 t4T[4], m0T[8];
#pragma unroll
  for (int nt = 0; nt < 4; ++nt) {
    acc2 ct{}, cm{};
#pragma unroll
    for (int ks = 0; ks < 4; ++ks) {
      gemmT(afrag(bufB + 8704, RS64, LO64, nt, ks, lane), X[ks],  ct);
      gemmT(afrag(bufB,        RS64, LO64, nt, ks, lane), Xa[ks], cm);
    }
    t4T[nt] = fin(ct);
    m0T[nt] = fin(cm);
  }

  // a1[u] = sum_m x1[u][m]*y1[m], features u = 16ks+4kgrp+(0..3)
  bpair A1[4];
#pragma unroll
  for (int ks = 0; ks < 4; ++ks) {
    const float* p = xr + 64 + (16*ks + 4*kgrp)*3;
    f32x4 q0 = *(const f32x4*)p, q1 = *(const f32x4*)(p+4), q2 = *(const f32x4*)(p+8);
    float vv[12];
#pragma unroll
    for (int i = 0; i < 4; ++i) { vv[i] = q0[i]; vv[4+i] = q1[i]; vv[8+i] = q2[i]; }
    f32x4 a;
#pragma unroll
    for (int e = 0; e < 4; ++e)
      a[e] = vv[3*e]*y1A0 + vv[3*e+1]*y1A1 + vv[3*e+2]*y1A2;
    A1[ks] = splitB(a);
  }
#pragma unroll
  for (int nt = 0; nt < 4; ++nt) {
    acc2 c{};
#pragma unroll
    for (int ks = 0; ks < 4; ++ks)
      gemmT(afrag(bufB + 17408, RS64, LO64, nt, ks, lane), A1[ks], c);
    m0T[4 + nt] = fin(c);
  }

  __syncthreads();                                   // B free, P5 arrived
  copyimg(bufB, wsrc + IMG_P6, 50, wave, lane);      // P6 under out0

  // ---- out0^T = LIN0^T @ (mid0 .* w0)^T  (K=128 = 8 k-steps) ----
  bpair S[8];
#pragma unroll
  for (int ks = 0; ks < 8; ++ks)
    S[ks] = splitB(m0T[ks] * wv[ks]);
#pragma unroll
  for (int nt = 0; nt < 4; ++nt) {
    acc2 c{};
#pragma unroll
    for (int ks = 0; ks < 8; ++ks)
      gemmT(afrag(bufA, RS128, LO128, nt, ks, lane), S[ks], c);
    if (active)
      *(f32x4*)(out + (size_t)rowg*256 + nt*16 + kgrp*4) = fin(c);   // 16B store
  }

  __syncthreads();                                   // P6 arrived

  // ---- per-m: mb^T = TP3^T @ (x1_m*y0)^T ; out1_m^T = LIN1^T @ (mid1_m .* w1)^T
  f32x4 o1f[3][4];
#pragma unroll
  for (int m = 0; m < 3; ++m) {
    const float y1m = (m == 0) ? y1A0 : (m == 1) ? y1A1 : y1A2;
    bpair C[4];
#pragma unroll
    for (int ks = 0; ks < 4; ++ks) {
      const float* p = xr + 64 + (16*ks + 4*kgrp)*3;   // L1-hot reload
      f32x4 q0 = *(const f32x4*)p, q1 = *(const f32x4*)(p+4), q2 = *(const f32x4*)(p+8);
      float vv[12];
#pragma unroll
      for (int i = 0; i < 4; ++i) { vv[i] = q0[i]; vv[4+i] = q1[i]; vv[8+i] = q2[i]; }
      f32x4 a;
#pragma unroll
      for (int e = 0; e < 4; ++e) a[e] = vv[3*e + m] * y0A;
      C[ks] = splitB(a);
    }
    f32x4 mbT[4];
#pragma unroll
    for (int nt = 0; nt < 4; ++nt) {
      acc2 c{};
#pragma unroll
      for (int ks = 0; ks < 4; ++ks)
        gemmT(afrag(bufB, RS64, LO64, nt, ks, lane), C[ks], c);
      mbT[nt] = fin(c);
    }

    bpair S1[8];
#pragma unroll
    for (int ks = 0; ks < 4; ++ks)
      S1[ks] = splitB(t4T[ks] * y1m * wv[8 + ks]);
#pragma unroll
    for (int ks = 0; ks < 4; ++ks)
      S1[4 + ks] = splitB(mbT[ks] * wv[12 + ks]);
#pragma unroll
    for (int nt = 0; nt < 4; ++nt) {
      acc2 c{};
#pragma unroll
      for (int ks = 0; ks < 8; ++ks)
        gemmT(afrag(bufB + 8704, RS128, LO128, nt, ks, lane), S1[ks], c);
      o1f[m][nt] = fin(c);
    }
  }

  if (active) {
#pragma unroll
    for (int nt = 0; nt < 4; ++nt)
#pragma unroll
      for (int r = 0; r < 4; ++r) {
        float* p = out + (size_t)rowg*256 + 64 + (nt*16 + kgrp*4 + r)*3;
        p[0] = o1f[0][nt][r];
        p[1] = o1f[1][nt][r];
        p[2] = o1f[2][nt][r];
      }
  }
}

extern "C" void kernel_launch(void* const* d_in, const int* in_sizes, int n_in,
                              void* d_out, int out_size, void* d_ws, size_t ws_size,
                              hipStream_t stream) {
  (void)in_sizes; (void)n_in; (void)out_size; (void)ws_size;
  _Float16* ws = (_Float16*)d_ws;
  prep_w<<<224, 256, 0, stream>>>(
      (const float*)d_in[3],  (const float*)d_in[4],  (const float*)d_in[5],
      (const float*)d_in[6],  (const float*)d_in[7],  (const float*)d_in[8],
      (const float*)d_in[9],  (const float*)d_in[10], (const float*)d_in[11], ws);
  tp_fused<<<NBLK, TPB, 0, stream>>>(
      (const float*)d_in[0],  (const float*)d_in[1],  (const float*)d_in[2],
      ws, (float*)d_out);
}